// Round 6
// baseline (179.638 us; speedup 1.0000x reference)
//
#include <hip/hip_runtime.h>
#include <math.h>

#define T_DIM 2048
#define C_DIM 1024
#define H_DIM 64
#define M_TOTAL 16384            // B*T
#define NQKV 192                 // k(0..63) | q(64..127) | v(128..191)
#define LROW 140                 // LDS row stride in shorts (280 B: k 0..63, v 64..127, pad)

typedef __bf16 bf16x8 __attribute__((ext_vector_type(8)));
typedef float f32x4 __attribute__((ext_vector_type(4)));
typedef unsigned short u16x8 __attribute__((ext_vector_type(8)));

__device__ __forceinline__ unsigned short f2bf(float f) {
    unsigned u = __float_as_uint(f);
    unsigned r = (u + 0x7FFFu + ((u >> 16) & 1u)) >> 16;   // RNE
    return (unsigned short)r;
}
__device__ __forceinline__ float bf2f(unsigned short u) {
    return __uint_as_float(((unsigned)u) << 16);
}
__device__ __forceinline__ float blo(unsigned u) { return __uint_as_float(u << 16); }
__device__ __forceinline__ float bhi(unsigned u) { return __uint_as_float(u & 0xFFFF0000u); }
// pack 2 floats -> 2 bf16 bits (round-half-up): 2x v_add + 1x v_perm
__device__ __forceinline__ unsigned pack_bf2(float f0, float f1) {
    unsigned u0 = __float_as_uint(f0) + 0x8000u;
    unsigned u1 = __float_as_uint(f1) + 0x8000u;
    return __builtin_amdgcn_perm(u1, u0, 0x07060302u);
}
__device__ __forceinline__ uint4 cvt8(float4 a, float4 b) {
    return make_uint4(pack_bf2(a.x, a.y), pack_bf2(a.z, a.w),
                      pack_bf2(b.x, b.y), pack_bf2(b.z, b.w));
}

// ---------------------------------------------------------------------------
// Kernel 1: fused convert + bf16 MFMA QKV projection (unchanged from R4/R5).
// ---------------------------------------------------------------------------
__global__ __launch_bounds__(512) void proj_kernel(
    const float* __restrict__ x,
    const float* __restrict__ Wk,
    const float* __restrict__ Wq,
    const float* __restrict__ Wv,
    unsigned short* __restrict__ qkv)   // [16384][192] bf16 bits
{
    __shared__ unsigned short Ab[64 * 64];    // [row][k^swz]
    __shared__ unsigned short Bb[192 * 64];   // [col][k^swz]

    const int m0 = blockIdx.x * 64;
    const int t  = threadIdx.x;
    const int wv = t >> 6, ln = t & 63;
    const int mfr = ln & 15, kq = ln >> 4;
    const int r0 = (wv & 1) * 32;
    const int c0 = (wv >> 1) * 48;

    const int srow  = t >> 3;                // 0..63
    const int sk8   = (t & 7) * 8;
    const int skoff = sk8 ^ ((srow & 7) * 8);

    const float* gp[4] = {
        x  + (size_t)(m0 + srow) * C_DIM + sk8,
        Wk + (size_t)srow * C_DIM + sk8,
        Wq + (size_t)srow * C_DIM + sk8,
        Wv + (size_t)srow * C_DIM + sk8 };
    unsigned short* lp[4] = {
        &Ab[srow * 64 + skoff],
        &Bb[srow * 64 + skoff],
        &Bb[(srow + 64) * 64 + skoff],
        &Bb[(srow + 128) * 64 + skoff] };

    f32x4 acc[2][3] = {};

    float4 ra[4], rb[4];
    #pragma unroll
    for (int s = 0; s < 4; ++s) {
        ra[s] = *(const float4*)(gp[s]);
        rb[s] = *(const float4*)(gp[s] + 4);
    }

    for (int kc = 0; kc < C_DIM; kc += 64) {
        __syncthreads();
        #pragma unroll
        for (int s = 0; s < 4; ++s)
            *(uint4*)lp[s] = cvt8(ra[s], rb[s]);
        if (kc + 64 < C_DIM) {
            #pragma unroll
            for (int s = 0; s < 4; ++s) {
                ra[s] = *(const float4*)(gp[s] + kc + 64);
                rb[s] = *(const float4*)(gp[s] + kc + 68);
            }
        }
        __syncthreads();
        #pragma unroll
        for (int ks = 0; ks < 64; ks += 32) {
            bf16x8 af[2], bf[3];
            #pragma unroll
            for (int a = 0; a < 2; ++a) {
                int row = r0 + a * 16 + mfr;
                af[a] = *(const bf16x8*)&Ab[row * 64 + ((ks + kq * 8) ^ ((row & 7) * 8))];
            }
            #pragma unroll
            for (int b2 = 0; b2 < 3; ++b2) {
                int row = c0 + b2 * 16 + mfr;
                bf[b2] = *(const bf16x8*)&Bb[row * 64 + ((ks + kq * 8) ^ ((row & 7) * 8))];
            }
            #pragma unroll
            for (int a = 0; a < 2; ++a)
                #pragma unroll
                for (int b2 = 0; b2 < 3; ++b2)
                    acc[a][b2] = __builtin_amdgcn_mfma_f32_16x16x32_bf16(
                        af[a], bf[b2], acc[a][b2], 0, 0, 0);
        }
    }

    #pragma unroll
    for (int a = 0; a < 2; ++a)
        #pragma unroll
        for (int b2 = 0; b2 < 3; ++b2)
            #pragma unroll
            for (int r = 0; r < 4; ++r) {
                int row = m0 + r0 + a * 16 + kq * 4 + r;
                int col = c0 + b2 * 16 + mfr;
                qkv[(size_t)row * NQKV + col] = f2bf(acc[a][b2][r]);
            }
}

// ---------------------------------------------------------------------------
// Kernel 2: sparse BigBird attention with shared-row LDS staging.
// Block = 16 consecutive queries of one batch. Staged rows: global 0..63
// (slots 0..63) + local band max(64, i0-63)..i0+15 (slots 64..). Each wave
// runs 4 queries sequentially with the proven per-query pipeline; local and
// global QK/PV read LDS, randoms stay on the (XCD-local) L2 gather path.
// ---------------------------------------------------------------------------
__global__ __launch_bounds__(256) void attn_kernel(
    const unsigned short* __restrict__ qkv,   // bf16 bits [16384][192]
    const int*  __restrict__ rnd,             // [2048][64]
    float* __restrict__ out)                  // [16384][64]
{
    __shared__ unsigned short Ks[143 * LROW]; // 40040 B: k|v per staged row
    __shared__ int2     cl_all[4][192];
    __shared__ unsigned bm_all[4][64];

    const int t  = threadIdx.x;
    const int wv = t >> 6;
    const int ln = t & 63;
    const int b  = blockIdx.x & 7;                  // XCD-locality swizzle
    const int i0 = (blockIdx.x >> 3) << 4;          // first query of block
    const int Lb = (i0 - 63 > 64) ? (i0 - 63) : 64; // band base (>=64 part)
    int nL = i0 + 16 - Lb; if (nL < 0) nL = 0;
    const int S_rows = 64 + nL;

    const unsigned short* kb = qkv + (size_t)b * T_DIM * NQKV;

    // ---- stage shared rows: 8 lanes per row, 16B k + 16B v per lane ----
    {
        const int u  = t >> 3;           // 0..31
        const int c8 = (t & 7) * 8;
        for (int s = u; s < S_rows; s += 32) {
            int j = (s < 64) ? s : (Lb + (s - 64));
            const unsigned short* src = kb + (size_t)j * NQKV;
            uint4 kk = *(const uint4*)(src + c8);
            uint4 vv = *(const uint4*)(src + 128 + c8);
            *(uint2*)&Ks[s * LROW + c8]          = make_uint2(kk.x, kk.y);
            *(uint2*)&Ks[s * LROW + c8 + 4]      = make_uint2(kk.z, kk.w);
            *(uint2*)&Ks[s * LROW + 64 + c8]     = make_uint2(vv.x, vv.y);
            *(uint2*)&Ks[s * LROW + 64 + c8 + 4] = make_uint2(vv.z, vv.w);
        }
    }
    __syncthreads();

    int2*     cl = cl_all[wv];
    unsigned* bm = bm_all[wv];
    const int e8 = (ln & 7) * 8;     // h-slice base for this lane
    const int gg = ln >> 3;          // row-group within instruction 0..7

    for (int qq = 0; qq < 4; ++qq) {
        const int i  = i0 + wv * 4 + qq;
        const int bi = b * T_DIM + i;

        bm[ln] = 0u;

        // ---- candidate table ----
        int  j0 = i - ln;            bool v0 = (j0 >= 0); if (!v0) j0 = 0;
        int  j1 = ln;                bool v1 = (j1 < i - 63);
        int  j2 = rnd[i * 64 + ln];  bool v2 = (j2 < i - 63) && (j2 >= 64);
        if (v2) {   // dedup among randoms
            unsigned old = atomicOr(&bm[j2 >> 5], 1u << (j2 & 31));
            v2 = ((old >> (j2 & 31)) & 1u) == 0u;
        }
        cl[ln]       = make_int2(j0, 0);
        cl[64 + ln]  = make_int2(j1, 0);
        cl[128 + ln] = make_int2(j2, 0);

        // ---- q h-slice in registers ----
        uint4 qv4 = *(const uint4*)(qkv + (size_t)bi * NQKV + 64 + e8);
        float qr[8] = { blo(qv4.x), bhi(qv4.x), blo(qv4.y), bhi(qv4.y),
                        blo(qv4.z), bhi(qv4.z), blo(qv4.w), bhi(qv4.w) };

        // ---- QK local+global from LDS (batches 0..15) ----
        #pragma unroll
        for (int n = 0; n < 16; n += 4) {
            int sl[4];
            #pragma unroll
            for (int u = 0; u < 4; ++u) {
                int j = cl[(n + u) * 8 + gg].x;
                sl[u] = (j < 64) ? j : (64 + j - Lb);
            }
            uint2 ka[4], kc[4];
            #pragma unroll
            for (int u = 0; u < 4; ++u) {
                ka[u] = *(const uint2*)&Ks[sl[u] * LROW + e8];
                kc[u] = *(const uint2*)&Ks[sl[u] * LROW + e8 + 4];
            }
            #pragma unroll
            for (int u = 0; u < 4; ++u) {
                float p = 0.f;
                p = fmaf(qr[0], blo(ka[u].x), p); p = fmaf(qr[1], bhi(ka[u].x), p);
                p = fmaf(qr[2], blo(ka[u].y), p); p = fmaf(qr[3], bhi(ka[u].y), p);
                p = fmaf(qr[4], blo(kc[u].x), p); p = fmaf(qr[5], bhi(kc[u].x), p);
                p = fmaf(qr[6], blo(kc[u].y), p); p = fmaf(qr[7], bhi(kc[u].y), p);
                p += __shfl_xor(p, 1);
                p += __shfl_xor(p, 2);
                p += __shfl_xor(p, 4);
                if ((ln & 7) == 0) cl[(n + u) * 8 + gg].y = __float_as_int(p);
            }
        }
        // ---- QK randoms from global (batches 16..23) ----
        #pragma unroll
        for (int n = 16; n < 24; n += 4) {
            int jj[4];
            #pragma unroll
            for (int u = 0; u < 4; ++u) jj[u] = cl[(n + u) * 8 + gg].x;
            u16x8 kv[4];
            #pragma unroll
            for (int u = 0; u < 4; ++u)
                kv[u] = *(const u16x8*)(kb + (size_t)jj[u] * NQKV + e8);
            #pragma unroll
            for (int u = 0; u < 4; ++u) {
                float p = 0.f;
                #pragma unroll
                for (int e = 0; e < 8; ++e) p = fmaf(qr[e], bf2f(kv[u][e]), p);
                p += __shfl_xor(p, 1);
                p += __shfl_xor(p, 2);
                p += __shfl_xor(p, 4);
                if ((ln & 7) == 0) cl[(n + u) * 8 + gg].y = __float_as_int(p);
            }
        }

        // ---- softmax over this lane's 3 candidates ----
        float s0 = __int_as_float(cl[ln].y);
        float s1 = __int_as_float(cl[64 + ln].y);
        float s2 = __int_as_float(cl[128 + ln].y);
        s0 = v0 ? s0 * 0.125f : -1e30f;
        s1 = v1 ? s1 * 0.125f : -1e30f;
        s2 = v2 ? s2 * 0.125f : -1e30f;

        float mx = fmaxf(s0, fmaxf(s1, s2));
        #pragma unroll
        for (int m = 32; m; m >>= 1) mx = fmaxf(mx, __shfl_xor(mx, m));
        float e0 = v0 ? __expf(s0 - mx) : 0.f;
        float e1 = v1 ? __expf(s1 - mx) : 0.f;
        float e2 = v2 ? __expf(s2 - mx) : 0.f;
        float sum = e0 + e1 + e2;
        #pragma unroll
        for (int m = 32; m; m >>= 1) sum += __shfl_xor(sum, m);

        cl[ln].y       = __float_as_int(e0);
        cl[64 + ln].y  = __float_as_int(e1);
        cl[128 + ln].y = __float_as_int(e2);

        // ---- PV: local+global from LDS, randoms from global ----
        float acc[8] = {};
        #pragma unroll
        for (int bt = 0; bt < 2; ++bt) {
            int2 p[8];
            #pragma unroll
            for (int c = 0; c < 8; ++c) p[c] = cl[(bt * 8 + c) * 8 + gg];
            uint2 va[8], vc[8];
            #pragma unroll
            for (int c = 0; c < 8; ++c) {
                int j = p[c].x;
                int s = (j < 64) ? j : (64 + j - Lb);
                va[c] = *(const uint2*)&Ks[s * LROW + 64 + e8];
                vc[c] = *(const uint2*)&Ks[s * LROW + 64 + e8 + 4];
            }
            #pragma unroll
            for (int c = 0; c < 8; ++c) {
                float w = __int_as_float(p[c].y);
                acc[0] = fmaf(w, blo(va[c].x), acc[0]);
                acc[1] = fmaf(w, bhi(va[c].x), acc[1]);
                acc[2] = fmaf(w, blo(va[c].y), acc[2]);
                acc[3] = fmaf(w, bhi(va[c].y), acc[3]);
                acc[4] = fmaf(w, blo(vc[c].x), acc[4]);
                acc[5] = fmaf(w, bhi(vc[c].x), acc[5]);
                acc[6] = fmaf(w, blo(vc[c].y), acc[6]);
                acc[7] = fmaf(w, bhi(vc[c].y), acc[7]);
            }
        }
        {   // randoms (cl slots 128..191)
            int2 p[8];
            #pragma unroll
            for (int c = 0; c < 8; ++c) p[c] = cl[(16 + c) * 8 + gg];
            u16x8 vvv[8];
            #pragma unroll
            for (int c = 0; c < 8; ++c)
                vvv[c] = *(const u16x8*)(kb + (size_t)p[c].x * NQKV + 128 + e8);
            #pragma unroll
            for (int c = 0; c < 8; ++c) {
                float w = __int_as_float(p[c].y);
                #pragma unroll
                for (int e = 0; e < 8; ++e)
                    acc[e] = fmaf(w, bf2f(vvv[c][e]), acc[e]);
            }
        }
        // reduce across the 8 row-groups
        #pragma unroll
        for (int m = 8; m <= 32; m <<= 1)
            #pragma unroll
            for (int e = 0; e < 8; ++e)
                acc[e] += __shfl_xor(acc[e], m);

        if (ln < 8) {
            float inv = 1.f / sum;
            float* op = &out[(size_t)bi * H_DIM + e8];
            *(float4*)op       = make_float4(acc[0]*inv, acc[1]*inv, acc[2]*inv, acc[3]*inv);
            *(float4*)(op + 4) = make_float4(acc[4]*inv, acc[5]*inv, acc[6]*inv, acc[7]*inv);
        }
    }
}

// ---------------------------------------------------------------------------
extern "C" void kernel_launch(void* const* d_in, const int* in_sizes, int n_in,
                              void* d_out, int out_size, void* d_ws, size_t ws_size,
                              hipStream_t stream) {
    const float* x   = (const float*)d_in[0];
    const int*   rnd = (const int*)  d_in[1];
    const float* Wk  = (const float*)d_in[2];
    const float* Wq  = (const float*)d_in[3];
    const float* Wv  = (const float*)d_in[4];
    float* out = (float*)d_out;
    unsigned short* qkv = (unsigned short*)d_ws;   // 16384*192*2 = 6.3 MB

    proj_kernel<<<M_TOTAL / 64, 512, 0, stream>>>(x, Wk, Wq, Wv, qkv);
    attn_kernel<<<M_TOTAL / 16, 256, 0, stream>>>(qkv, rnd, out);
}

// Round 7
// 167.038 us; speedup vs baseline: 1.0754x; 1.0754x over previous
//
#include <hip/hip_runtime.h>
#include <math.h>

#define T_DIM 2048
#define C_DIM 1024
#define H_DIM 64
#define M_TOTAL 16384            // B*T
#define NQKV 192                 // k(0..63) | q(64..127) | v(128..191)

typedef __bf16 bf16x8 __attribute__((ext_vector_type(8)));
typedef float f32x4 __attribute__((ext_vector_type(4)));
typedef unsigned short u16x8 __attribute__((ext_vector_type(8)));

__device__ __forceinline__ unsigned short f2bf(float f) {
    unsigned u = __float_as_uint(f);
    unsigned r = (u + 0x7FFFu + ((u >> 16) & 1u)) >> 16;   // RNE
    return (unsigned short)r;
}
__device__ __forceinline__ float bf2f(unsigned short u) {
    return __uint_as_float(((unsigned)u) << 16);
}
// pack 2 floats -> 2 bf16 bits (round-half-up): 2x v_add + 1x v_perm
__device__ __forceinline__ unsigned pack_bf2(float f0, float f1) {
    unsigned u0 = __float_as_uint(f0) + 0x8000u;
    unsigned u1 = __float_as_uint(f1) + 0x8000u;
    return __builtin_amdgcn_perm(u1, u0, 0x07060302u);
}
__device__ __forceinline__ uint4 cvt8(float4 a, float4 b) {
    return make_uint4(pack_bf2(a.x, a.y), pack_bf2(a.z, a.w),
                      pack_bf2(b.x, b.y), pack_bf2(b.z, b.w));
}

// ---------------------------------------------------------------------------
// Kernel 1: fused convert + bf16 MFMA QKV projection (unchanged from R4/R5).
// ---------------------------------------------------------------------------
__global__ __launch_bounds__(512) void proj_kernel(
    const float* __restrict__ x,
    const float* __restrict__ Wk,
    const float* __restrict__ Wq,
    const float* __restrict__ Wv,
    unsigned short* __restrict__ qkv)   // [16384][192] bf16 bits
{
    __shared__ unsigned short Ab[64 * 64];    // [row][k^swz]
    __shared__ unsigned short Bb[192 * 64];   // [col][k^swz]

    const int m0 = blockIdx.x * 64;
    const int t  = threadIdx.x;
    const int wv = t >> 6, ln = t & 63;
    const int mfr = ln & 15, kq = ln >> 4;
    const int r0 = (wv & 1) * 32;
    const int c0 = (wv >> 1) * 48;

    const int srow  = t >> 3;                // 0..63
    const int sk8   = (t & 7) * 8;
    const int skoff = sk8 ^ ((srow & 7) * 8);

    const float* gp[4] = {
        x  + (size_t)(m0 + srow) * C_DIM + sk8,
        Wk + (size_t)srow * C_DIM + sk8,
        Wq + (size_t)srow * C_DIM + sk8,
        Wv + (size_t)srow * C_DIM + sk8 };
    unsigned short* lp[4] = {
        &Ab[srow * 64 + skoff],
        &Bb[srow * 64 + skoff],
        &Bb[(srow + 64) * 64 + skoff],
        &Bb[(srow + 128) * 64 + skoff] };

    f32x4 acc[2][3] = {};

    float4 ra[4], rb[4];
    #pragma unroll
    for (int s = 0; s < 4; ++s) {
        ra[s] = *(const float4*)(gp[s]);
        rb[s] = *(const float4*)(gp[s] + 4);
    }

    for (int kc = 0; kc < C_DIM; kc += 64) {
        __syncthreads();
        #pragma unroll
        for (int s = 0; s < 4; ++s)
            *(uint4*)lp[s] = cvt8(ra[s], rb[s]);
        if (kc + 64 < C_DIM) {
            #pragma unroll
            for (int s = 0; s < 4; ++s) {
                ra[s] = *(const float4*)(gp[s] + kc + 64);
                rb[s] = *(const float4*)(gp[s] + kc + 68);
            }
        }
        __syncthreads();
        #pragma unroll
        for (int ks = 0; ks < 64; ks += 32) {
            bf16x8 af[2], bf[3];
            #pragma unroll
            for (int a = 0; a < 2; ++a) {
                int row = r0 + a * 16 + mfr;
                af[a] = *(const bf16x8*)&Ab[row * 64 + ((ks + kq * 8) ^ ((row & 7) * 8))];
            }
            #pragma unroll
            for (int b2 = 0; b2 < 3; ++b2) {
                int row = c0 + b2 * 16 + mfr;
                bf[b2] = *(const bf16x8*)&Bb[row * 64 + ((ks + kq * 8) ^ ((row & 7) * 8))];
            }
            #pragma unroll
            for (int a = 0; a < 2; ++a)
                #pragma unroll
                for (int b2 = 0; b2 < 3; ++b2)
                    acc[a][b2] = __builtin_amdgcn_mfma_f32_16x16x32_bf16(
                        af[a], bf[b2], acc[a][b2], 0, 0, 0);
        }
    }

    #pragma unroll
    for (int a = 0; a < 2; ++a)
        #pragma unroll
        for (int b2 = 0; b2 < 3; ++b2)
            #pragma unroll
            for (int r = 0; r < 4; ++r) {
                int row = m0 + r0 + a * 16 + kq * 4 + r;
                int col = c0 + b2 * 16 + mfr;
                qkv[(size_t)row * NQKV + col] = f2bf(acc[a][b2][r]);
            }
}

// ---------------------------------------------------------------------------
// Kernel 2: sparse BigBird attention, TWO consecutive queries per wave.
// Barrier-free (all LDS per-wave). Shared gathers: local-band union (9
// instrs) + globals (8) feed both queries' scores; randoms per-query.
// VMEM/pair = 70 vs 100. High occupancy preserved (14.3KB LDS, ~70 VGPR).
// ---------------------------------------------------------------------------
__global__ __launch_bounds__(256) void attn_kernel(
    const unsigned short* __restrict__ qkv,   // bf16 bits [16384][192]
    const int*  __restrict__ rnd,             // [2048][64]
    float* __restrict__ out)                  // [16384][64]
{
    const int wv = threadIdx.x >> 6;
    const int ln = threadIdx.x & 63;
    const int b  = blockIdx.x & 7;                     // XCD-locality swizzle
    const int iA = ((blockIdx.x >> 3) << 3) + wv * 2;  // 0..2046 (even)
    const int iB = iA + 1;
    const int biA = b * T_DIM + iA;

    __shared__ int2     clA_all[4][192], clB_all[4][192];
    __shared__ unsigned bmA_all[4][64],  bmB_all[4][64];
    int2*     clA = clA_all[wv];
    int2*     clB = clB_all[wv];
    unsigned* bmA = bmA_all[wv];
    unsigned* bmB = bmB_all[wv];

    bmA[ln] = 0u;
    bmB[ln] = 0u;

    // ---- per-query candidate validity (registers) ----
    int  j0A = iA - ln;            bool v0A = (j0A >= 0);
    int  j0B = iB - ln;            bool v0B = (j0B >= 0);
    bool v1A = (ln < iA - 63);
    bool v1B = (ln < iB - 63);
    int  j2A = rnd[iA * 64 + ln];  bool v2A = (j2A < iA - 63) && (j2A >= 64);
    int  j2B = rnd[iB * 64 + ln];  bool v2B = (j2B < iB - 63) && (j2B >= 64);
    if (v2A) {
        unsigned old = atomicOr(&bmA[j2A >> 5], 1u << (j2A & 31));
        v2A = ((old >> (j2A & 31)) & 1u) == 0u;
    }
    if (v2B) {
        unsigned old = atomicOr(&bmB[j2B >> 5], 1u << (j2B & 31));
        v2B = ((old >> (j2B & 31)) & 1u) == 0u;
    }
    clA[128 + ln] = make_int2(j2A, 0);
    clB[128 + ln] = make_int2(j2B, 0);

    // ---- q h-slices in registers for both queries ----
    const int e8 = (ln & 7) * 8;     // h-slice base
    const int gg = ln >> 3;          // row-group within instruction 0..7
    u16x8 qrawA = *(const u16x8*)(qkv + (size_t)biA * NQKV + 64 + e8);
    u16x8 qrawB = *(const u16x8*)(qkv + (size_t)(biA + 1) * NQKV + 64 + e8);
    float qA[8], qB[8];
    #pragma unroll
    for (int e = 0; e < 8; ++e) { qA[e] = bf2f(qrawA[e]); qB[e] = bf2f(qrawB[e]); }

    const unsigned short* kb = qkv + (size_t)b * T_DIM * NQKV;

    // ---- QK local-band union: rows j = iA-63+r, r = n*8+gg, n = 0..8 ----
    #pragma unroll
    for (int n0 = 0; n0 < 9; n0 += 3) {
        const int nn = (n0 + 3 <= 9) ? 3 : (9 - n0);
        int rr[3]; u16x8 kv[3];
        #pragma unroll
        for (int u = 0; u < 3; ++u) {
            if (u < nn) {
                rr[u] = (n0 + u) * 8 + gg;
                int j = iA - 63 + rr[u];
                int jc = j < 0 ? 0 : (j > T_DIM - 1 ? T_DIM - 1 : j);
                kv[u] = *(const u16x8*)(kb + (size_t)jc * NQKV + e8);
            }
        }
        #pragma unroll
        for (int u = 0; u < 3; ++u) {
            if (u < nn) {
                float pA = 0.f, pB = 0.f;
                #pragma unroll
                for (int e = 0; e < 8; ++e) {
                    float kvf = bf2f(kv[u][e]);
                    pA = fmaf(qA[e], kvf, pA);
                    pB = fmaf(qB[e], kvf, pB);
                }
                pA += __shfl_xor(pA, 1); pB += __shfl_xor(pB, 1);
                pA += __shfl_xor(pA, 2); pB += __shfl_xor(pB, 2);
                pA += __shfl_xor(pA, 4); pB += __shfl_xor(pB, 4);
                if ((ln & 7) == 0) {
                    int lA = 63 - rr[u];            // A's local slot
                    int lB = 64 - rr[u];            // B's local slot
                    if (lA >= 0)            clA[lA].y = __float_as_int(pA);
                    if (lB >= 0 && lB < 64) clB[lB].y = __float_as_int(pB);
                }
            }
        }
    }

    // ---- QK globals: rows j = n*8+gg, n = 0..7, shared by A and B ----
    #pragma unroll
    for (int n0 = 0; n0 < 8; n0 += 4) {
        u16x8 kv[4];
        #pragma unroll
        for (int u = 0; u < 4; ++u)
            kv[u] = *(const u16x8*)(kb + (size_t)((n0 + u) * 8 + gg) * NQKV + e8);
        #pragma unroll
        for (int u = 0; u < 4; ++u) {
            float pA = 0.f, pB = 0.f;
            #pragma unroll
            for (int e = 0; e < 8; ++e) {
                float kvf = bf2f(kv[u][e]);
                pA = fmaf(qA[e], kvf, pA);
                pB = fmaf(qB[e], kvf, pB);
            }
            pA += __shfl_xor(pA, 1); pB += __shfl_xor(pB, 1);
            pA += __shfl_xor(pA, 2); pB += __shfl_xor(pB, 2);
            pA += __shfl_xor(pA, 4); pB += __shfl_xor(pB, 4);
            if ((ln & 7) == 0) {
                int j = (n0 + u) * 8 + gg;
                clA[64 + j].y = __float_as_int(pA);
                clB[64 + j].y = __float_as_int(pB);
            }
        }
    }

    // ---- QK randoms (per query) ----
    #pragma unroll
    for (int n0 = 16; n0 < 24; n0 += 4) {
        int jj[4]; u16x8 kv[4];
        #pragma unroll
        for (int u = 0; u < 4; ++u) jj[u] = clA[(n0 + u) * 8 + gg].x;
        #pragma unroll
        for (int u = 0; u < 4; ++u)
            kv[u] = *(const u16x8*)(kb + (size_t)jj[u] * NQKV + e8);
        #pragma unroll
        for (int u = 0; u < 4; ++u) {
            float p = 0.f;
            #pragma unroll
            for (int e = 0; e < 8; ++e) p = fmaf(qA[e], bf2f(kv[u][e]), p);
            p += __shfl_xor(p, 1); p += __shfl_xor(p, 2); p += __shfl_xor(p, 4);
            if ((ln & 7) == 0) clA[(n0 + u) * 8 + gg].y = __float_as_int(p);
        }
    }
    #pragma unroll
    for (int n0 = 16; n0 < 24; n0 += 4) {
        int jj[4]; u16x8 kv[4];
        #pragma unroll
        for (int u = 0; u < 4; ++u) jj[u] = clB[(n0 + u) * 8 + gg].x;
        #pragma unroll
        for (int u = 0; u < 4; ++u)
            kv[u] = *(const u16x8*)(kb + (size_t)jj[u] * NQKV + e8);
        #pragma unroll
        for (int u = 0; u < 4; ++u) {
            float p = 0.f;
            #pragma unroll
            for (int e = 0; e < 8; ++e) p = fmaf(qB[e], bf2f(kv[u][e]), p);
            p += __shfl_xor(p, 1); p += __shfl_xor(p, 2); p += __shfl_xor(p, 4);
            if ((ln & 7) == 0) clB[(n0 + u) * 8 + gg].y = __float_as_int(p);
        }
    }

    // ---- softmax per query (same-wave DS ordering; weights back to .y) ----
    float sumA, sumB;
    {
        float s0 = __int_as_float(clA[ln].y);
        float s1 = __int_as_float(clA[64 + ln].y);
        float s2 = __int_as_float(clA[128 + ln].y);
        s0 = v0A ? s0 * 0.125f : -1e30f;
        s1 = v1A ? s1 * 0.125f : -1e30f;
        s2 = v2A ? s2 * 0.125f : -1e30f;
        float mx = fmaxf(s0, fmaxf(s1, s2));
        #pragma unroll
        for (int m = 32; m; m >>= 1) mx = fmaxf(mx, __shfl_xor(mx, m));
        float e0 = v0A ? __expf(s0 - mx) : 0.f;
        float e1 = v1A ? __expf(s1 - mx) : 0.f;
        float e2 = v2A ? __expf(s2 - mx) : 0.f;
        float sm = e0 + e1 + e2;
        #pragma unroll
        for (int m = 32; m; m >>= 1) sm += __shfl_xor(sm, m);
        sumA = sm;
        clA[ln].y       = __float_as_int(e0);
        clA[64 + ln].y  = __float_as_int(e1);
        clA[128 + ln].y = __float_as_int(e2);
    }
    {
        float s0 = __int_as_float(clB[ln].y);
        float s1 = __int_as_float(clB[64 + ln].y);
        float s2 = __int_as_float(clB[128 + ln].y);
        s0 = v0B ? s0 * 0.125f : -1e30f;
        s1 = v1B ? s1 * 0.125f : -1e30f;
        s2 = v2B ? s2 * 0.125f : -1e30f;
        float mx = fmaxf(s0, fmaxf(s1, s2));
        #pragma unroll
        for (int m = 32; m; m >>= 1) mx = fmaxf(mx, __shfl_xor(mx, m));
        float e0 = v0B ? __expf(s0 - mx) : 0.f;
        float e1 = v1B ? __expf(s1 - mx) : 0.f;
        float e2 = v2B ? __expf(s2 - mx) : 0.f;
        float sm = e0 + e1 + e2;
        #pragma unroll
        for (int m = 32; m; m >>= 1) sm += __shfl_xor(sm, m);
        sumB = sm;
        clB[ln].y       = __float_as_int(e0);
        clB[64 + ln].y  = __float_as_int(e1);
        clB[128 + ln].y = __float_as_int(e2);
    }

    // ---- PV ----
    const unsigned short* vb = kb + 128;
    float accA[8] = {}, accB[8] = {};

    // local-band union rows (shared v loads)
    #pragma unroll
    for (int n0 = 0; n0 < 9; n0 += 3) {
        const int nn = (n0 + 3 <= 9) ? 3 : (9 - n0);
        int rr[3]; u16x8 vv[3];
        #pragma unroll
        for (int u = 0; u < 3; ++u) {
            if (u < nn) {
                rr[u] = (n0 + u) * 8 + gg;
                int j = iA - 63 + rr[u];
                int jc = j < 0 ? 0 : (j > T_DIM - 1 ? T_DIM - 1 : j);
                vv[u] = *(const u16x8*)(vb + (size_t)jc * NQKV + e8);
            }
        }
        #pragma unroll
        for (int u = 0; u < 3; ++u) {
            if (u < nn) {
                int lA = 63 - rr[u];
                int lB = 64 - rr[u];
                int lAc = lA < 0 ? 0 : lA;
                int lBc = (lB < 0) ? 0 : (lB > 63 ? 63 : lB);
                float wA = __int_as_float(clA[lAc].y);
                float wB = __int_as_float(clB[lBc].y);
                wA = (lA >= 0) ? wA : 0.f;
                wB = (lB >= 0 && lB < 64) ? wB : 0.f;
                #pragma unroll
                for (int e = 0; e < 8; ++e) {
                    float vf = bf2f(vv[u][e]);
                    accA[e] = fmaf(wA, vf, accA[e]);
                    accB[e] = fmaf(wB, vf, accB[e]);
                }
            }
        }
    }
    // global rows (shared v loads)
    #pragma unroll
    for (int n0 = 0; n0 < 8; n0 += 4) {
        u16x8 vv[4];
        #pragma unroll
        for (int u = 0; u < 4; ++u)
            vv[u] = *(const u16x8*)(vb + (size_t)((n0 + u) * 8 + gg) * NQKV + e8);
        #pragma unroll
        for (int u = 0; u < 4; ++u) {
            int j = (n0 + u) * 8 + gg;
            float wA = __int_as_float(clA[64 + j].y);
            float wB = __int_as_float(clB[64 + j].y);
            #pragma unroll
            for (int e = 0; e < 8; ++e) {
                float vf = bf2f(vv[u][e]);
                accA[e] = fmaf(wA, vf, accA[e]);
                accB[e] = fmaf(wB, vf, accB[e]);
            }
        }
    }
    // random rows (per query)
    #pragma unroll
    for (int n0 = 16; n0 < 24; n0 += 4) {
        int2 p[4]; u16x8 vv[4];
        #pragma unroll
        for (int u = 0; u < 4; ++u) p[u] = clA[(n0 + u) * 8 + gg];
        #pragma unroll
        for (int u = 0; u < 4; ++u)
            vv[u] = *(const u16x8*)(vb + (size_t)p[u].x * NQKV + e8);
        #pragma unroll
        for (int u = 0; u < 4; ++u) {
            float w = __int_as_float(p[u].y);
            #pragma unroll
            for (int e = 0; e < 8; ++e)
                accA[e] = fmaf(w, bf2f(vv[u][e]), accA[e]);
        }
    }
    #pragma unroll
    for (int n0 = 16; n0 < 24; n0 += 4) {
        int2 p[4]; u16x8 vv[4];
        #pragma unroll
        for (int u = 0; u < 4; ++u) p[u] = clB[(n0 + u) * 8 + gg];
        #pragma unroll
        for (int u = 0; u < 4; ++u)
            vv[u] = *(const u16x8*)(vb + (size_t)p[u].x * NQKV + e8);
        #pragma unroll
        for (int u = 0; u < 4; ++u) {
            float w = __int_as_float(p[u].y);
            #pragma unroll
            for (int e = 0; e < 8; ++e)
                accB[e] = fmaf(w, bf2f(vv[u][e]), accB[e]);
        }
    }

    // reduce across the 8 row-groups
    #pragma unroll
    for (int m = 8; m <= 32; m <<= 1)
        #pragma unroll
        for (int e = 0; e < 8; ++e) {
            accA[e] += __shfl_xor(accA[e], m);
            accB[e] += __shfl_xor(accB[e], m);
        }

    if (ln < 8) {
        float invA = 1.f / sumA, invB = 1.f / sumB;
        float* opA = &out[(size_t)biA * H_DIM + e8];
        *(float4*)opA       = make_float4(accA[0]*invA, accA[1]*invA, accA[2]*invA, accA[3]*invA);
        *(float4*)(opA + 4) = make_float4(accA[4]*invA, accA[5]*invA, accA[6]*invA, accA[7]*invA);
        float* opB = &out[(size_t)(biA + 1) * H_DIM + e8];
        *(float4*)opB       = make_float4(accB[0]*invB, accB[1]*invB, accB[2]*invB, accB[3]*invB);
        *(float4*)(opB + 4) = make_float4(accB[4]*invB, accB[5]*invB, accB[6]*invB, accB[7]*invB);
    }
}

// ---------------------------------------------------------------------------
extern "C" void kernel_launch(void* const* d_in, const int* in_sizes, int n_in,
                              void* d_out, int out_size, void* d_ws, size_t ws_size,
                              hipStream_t stream) {
    const float* x   = (const float*)d_in[0];
    const int*   rnd = (const int*)  d_in[1];
    const float* Wk  = (const float*)d_in[2];
    const float* Wq  = (const float*)d_in[3];
    const float* Wv  = (const float*)d_in[4];
    float* out = (float*)d_out;
    unsigned short* qkv = (unsigned short*)d_ws;   // 16384*192*2 = 6.3 MB

    proj_kernel<<<M_TOTAL / 64, 512, 0, stream>>>(x, Wk, Wq, Wv, qkv);
    attn_kernel<<<M_TOTAL / 8, 256, 0, stream>>>(qkv, rnd, out);
}

// Round 8
// 155.259 us; speedup vs baseline: 1.1570x; 1.0759x over previous
//
#include <hip/hip_runtime.h>
#include <math.h>

#define T_DIM 2048
#define C_DIM 1024
#define H_DIM 64
#define M_TOTAL 16384            // B*T
#define NQKV 192                 // k(0..63) | q(64..127) | v(128..191)

typedef __bf16 bf16x8 __attribute__((ext_vector_type(8)));
typedef float f32x4 __attribute__((ext_vector_type(4)));
typedef unsigned short u16x8 __attribute__((ext_vector_type(8)));

__device__ __forceinline__ unsigned short f2bf(float f) {
    unsigned u = __float_as_uint(f);
    unsigned r = (u + 0x7FFFu + ((u >> 16) & 1u)) >> 16;   // RNE
    return (unsigned short)r;
}
__device__ __forceinline__ float bf2f(unsigned short u) {
    return __uint_as_float(((unsigned)u) << 16);
}
// pack 2 floats -> 2 bf16 bits (round-half-up): 2x v_add + 1x v_perm
__device__ __forceinline__ unsigned pack_bf2(float f0, float f1) {
    unsigned u0 = __float_as_uint(f0) + 0x8000u;
    unsigned u1 = __float_as_uint(f1) + 0x8000u;
    return __builtin_amdgcn_perm(u1, u0, 0x07060302u);
}
__device__ __forceinline__ uint4 cvt8(float4 a, float4 b) {
    return make_uint4(pack_bf2(a.x, a.y), pack_bf2(a.z, a.w),
                      pack_bf2(b.x, b.y), pack_bf2(b.z, b.w));
}

// ---------------------------------------------------------------------------
// Kernel 1: fused convert + bf16 MFMA QKV projection (unchanged since R4).
// ---------------------------------------------------------------------------
__global__ __launch_bounds__(512) void proj_kernel(
    const float* __restrict__ x,
    const float* __restrict__ Wk,
    const float* __restrict__ Wq,
    const float* __restrict__ Wv,
    unsigned short* __restrict__ qkv)   // [16384][192] bf16 bits
{
    __shared__ unsigned short Ab[64 * 64];    // [row][k^swz]
    __shared__ unsigned short Bb[192 * 64];   // [col][k^swz]

    const int m0 = blockIdx.x * 64;
    const int t  = threadIdx.x;
    const int wv = t >> 6, ln = t & 63;
    const int mfr = ln & 15, kq = ln >> 4;
    const int r0 = (wv & 1) * 32;
    const int c0 = (wv >> 1) * 48;

    const int srow  = t >> 3;                // 0..63
    const int sk8   = (t & 7) * 8;
    const int skoff = sk8 ^ ((srow & 7) * 8);

    const float* gp[4] = {
        x  + (size_t)(m0 + srow) * C_DIM + sk8,
        Wk + (size_t)srow * C_DIM + sk8,
        Wq + (size_t)srow * C_DIM + sk8,
        Wv + (size_t)srow * C_DIM + sk8 };
    unsigned short* lp[4] = {
        &Ab[srow * 64 + skoff],
        &Bb[srow * 64 + skoff],
        &Bb[(srow + 64) * 64 + skoff],
        &Bb[(srow + 128) * 64 + skoff] };

    f32x4 acc[2][3] = {};

    float4 ra[4], rb[4];
    #pragma unroll
    for (int s = 0; s < 4; ++s) {
        ra[s] = *(const float4*)(gp[s]);
        rb[s] = *(const float4*)(gp[s] + 4);
    }

    for (int kc = 0; kc < C_DIM; kc += 64) {
        __syncthreads();
        #pragma unroll
        for (int s = 0; s < 4; ++s)
            *(uint4*)lp[s] = cvt8(ra[s], rb[s]);
        if (kc + 64 < C_DIM) {
            #pragma unroll
            for (int s = 0; s < 4; ++s) {
                ra[s] = *(const float4*)(gp[s] + kc + 64);
                rb[s] = *(const float4*)(gp[s] + kc + 68);
            }
        }
        __syncthreads();
        #pragma unroll
        for (int ks = 0; ks < 64; ks += 32) {
            bf16x8 af[2], bf[3];
            #pragma unroll
            for (int a = 0; a < 2; ++a) {
                int row = r0 + a * 16 + mfr;
                af[a] = *(const bf16x8*)&Ab[row * 64 + ((ks + kq * 8) ^ ((row & 7) * 8))];
            }
            #pragma unroll
            for (int b2 = 0; b2 < 3; ++b2) {
                int row = c0 + b2 * 16 + mfr;
                bf[b2] = *(const bf16x8*)&Bb[row * 64 + ((ks + kq * 8) ^ ((row & 7) * 8))];
            }
            #pragma unroll
            for (int a = 0; a < 2; ++a)
                #pragma unroll
                for (int b2 = 0; b2 < 3; ++b2)
                    acc[a][b2] = __builtin_amdgcn_mfma_f32_16x16x32_bf16(
                        af[a], bf[b2], acc[a][b2], 0, 0, 0);
        }
    }

    #pragma unroll
    for (int a = 0; a < 2; ++a)
        #pragma unroll
        for (int b2 = 0; b2 < 3; ++b2)
            #pragma unroll
            for (int r = 0; r < 4; ++r) {
                int row = m0 + r0 + a * 16 + kq * 4 + r;
                int col = c0 + b2 * 16 + mfr;
                qkv[(size_t)row * NQKV + col] = f2bf(acc[a][b2][r]);
            }
}

// ---------------------------------------------------------------------------
// Kernel 2: sparse BigBird attention (R5 structure: one wave per query,
// barrier-free, XCD swizzle, 8-lanes-per-row gathers) + random-candidate
// compaction: only the ~44% valid randoms are gathered (ballot+popc compact,
// wave-uniform batch count). Slot-based validity for randoms (ln < nval).
// ---------------------------------------------------------------------------
__global__ __launch_bounds__(256) void attn_kernel(
    const unsigned short* __restrict__ qkv,   // bf16 bits [16384][192]
    const int*  __restrict__ rnd,             // [2048][64]
    float* __restrict__ out)                  // [16384][64]
{
    const int wv = threadIdx.x >> 6;
    const int ln = threadIdx.x & 63;
    const int b  = blockIdx.x & 7;                  // XCD-locality swizzle
    const int i  = ((blockIdx.x >> 3) << 2) + wv;   // 0..2047
    const int bi = b * T_DIM + i;

    __shared__ int2     cl_all[4][192];   // (col, score/weight bits)
    __shared__ unsigned bm_all[4][64];
    int2*     cl = cl_all[wv];
    unsigned* bm = bm_all[wv];

    bm[ln] = 0u;

    // ---- candidate table ----
    int  j0 = i - ln;            bool v0 = (j0 >= 0); if (!v0) j0 = 0;
    bool v1 = (ln < i - 63);
    int  j2 = rnd[i * 64 + ln];  bool v2 = (j2 < i - 63) && (j2 >= 64);
    if (v2) {   // dedup among randoms: winner of atomicOr keeps the column
        unsigned old = atomicOr(&bm[j2 >> 5], 1u << (j2 & 31));
        v2 = ((old >> (j2 & 31)) & 1u) == 0u;
    }
    cl[ln]        = make_int2(j0, 0);
    cl[64 + ln]   = make_int2(ln, 0);
    cl[128 + ln]  = make_int2(0, 0);               // padding init (safe j=0)
    // compact valid randoms to slots 128..128+nval-1 (same-wave DS order)
    unsigned long long mb = __ballot(v2);
    const int nval = __popcll(mb);
    if (v2) {
        int pos = __popcll(mb & ((1ull << ln) - 1ull));
        cl[128 + pos] = make_int2(j2, 0);
    }
    const int nr8 = (nval + 7) >> 3;               // random gather batches

    // ---- q h-slice in registers ----
    const int e8 = (ln & 7) * 8;     // h-slice base for this lane
    const int gg = ln >> 3;          // row-group within instruction 0..7
    u16x8 qraw = *(const u16x8*)(qkv + (size_t)bi * NQKV + 64 + e8);
    float qr[8];
    #pragma unroll
    for (int e = 0; e < 8; ++e) qr[e] = bf2f(qraw[e]);

    const unsigned short* kb = qkv + (size_t)b * T_DIM * NQKV;

    // ---- QK local+global: 16 fixed batches, 4-way MLP ----
    #pragma unroll
    for (int n = 0; n < 16; n += 4) {
        int jj[4];
        #pragma unroll
        for (int u = 0; u < 4; ++u) jj[u] = cl[(n + u) * 8 + gg].x;
        u16x8 kv[4];
        #pragma unroll
        for (int u = 0; u < 4; ++u)
            kv[u] = *(const u16x8*)(kb + (size_t)jj[u] * NQKV + e8);
        #pragma unroll
        for (int u = 0; u < 4; ++u) {
            float p = 0.f;
            #pragma unroll
            for (int e = 0; e < 8; ++e) p = fmaf(qr[e], bf2f(kv[u][e]), p);
            p += __shfl_xor(p, 1);
            p += __shfl_xor(p, 2);
            p += __shfl_xor(p, 4);
            if ((ln & 7) == 0) cl[(n + u) * 8 + gg].y = __float_as_int(p);
        }
    }

    // ---- QK randoms: nr8 wave-uniform batches (avg ~3.5), 2-way MLP ----
    for (int n0 = 0; n0 < nr8; n0 += 2) {
        const bool a1 = (n0 + 1) < nr8;
        const int s0i = (16 + n0) * 8 + gg;
        const int s1i = s0i + 8;
        int ja = cl[s0i].x;
        int jb = a1 ? cl[s1i].x : 0;
        u16x8 ka = *(const u16x8*)(kb + (size_t)ja * NQKV + e8);
        u16x8 kc = *(const u16x8*)(kb + (size_t)jb * NQKV + e8);
        float pa = 0.f, pb = 0.f;
        #pragma unroll
        for (int e = 0; e < 8; ++e) {
            pa = fmaf(qr[e], bf2f(ka[e]), pa);
            pb = fmaf(qr[e], bf2f(kc[e]), pb);
        }
        pa += __shfl_xor(pa, 1); pb += __shfl_xor(pb, 1);
        pa += __shfl_xor(pa, 2); pb += __shfl_xor(pb, 2);
        pa += __shfl_xor(pa, 4); pb += __shfl_xor(pb, 4);
        if ((ln & 7) == 0) {
            cl[s0i].y = __float_as_int(pa);
            if (a1) cl[s1i].y = __float_as_int(pb);
        }
    }

    // ---- softmax: lane handles slots {ln, 64+ln, 128+ln} ----
    const bool vs2 = (ln < nval);
    float s0 = __int_as_float(cl[ln].y);
    float s1 = __int_as_float(cl[64 + ln].y);
    float s2 = __int_as_float(cl[128 + ln].y);
    s0 = v0  ? s0 * 0.125f : -1e30f;
    s1 = v1  ? s1 * 0.125f : -1e30f;
    s2 = vs2 ? s2 * 0.125f : -1e30f;

    float mx = fmaxf(s0, fmaxf(s1, s2));
    #pragma unroll
    for (int m = 32; m; m >>= 1) mx = fmaxf(mx, __shfl_xor(mx, m));
    float e0 = v0  ? __expf(s0 - mx) : 0.f;
    float e1 = v1  ? __expf(s1 - mx) : 0.f;
    float e2 = vs2 ? __expf(s2 - mx) : 0.f;
    float sum = e0 + e1 + e2;
    #pragma unroll
    for (int m = 32; m; m >>= 1) sum += __shfl_xor(sum, m);

    cl[ln].y       = __float_as_int(e0);
    cl[64 + ln].y  = __float_as_int(e1);
    cl[128 + ln].y = __float_as_int(e2);

    // ---- PV local+global: 16 fixed batches, 8-way MLP ----
    const unsigned short* vb = kb + 128;
    float acc[8] = {};
    #pragma unroll
    for (int bt = 0; bt < 2; ++bt) {
        int2 p[8];
        #pragma unroll
        for (int c = 0; c < 8; ++c) p[c] = cl[(bt * 8 + c) * 8 + gg];
        u16x8 vvv[8];
        #pragma unroll
        for (int c = 0; c < 8; ++c)
            vvv[c] = *(const u16x8*)(vb + (size_t)p[c].x * NQKV + e8);
        #pragma unroll
        for (int c = 0; c < 8; ++c) {
            float w = __int_as_float(p[c].y);
            #pragma unroll
            for (int e = 0; e < 8; ++e)
                acc[e] = fmaf(w, bf2f(vvv[c][e]), acc[e]);
        }
    }
    // ---- PV randoms: nr8 batches (padded slots have weight 0) ----
    for (int n0 = 0; n0 < nr8; n0 += 2) {
        const bool a1 = (n0 + 1) < nr8;
        int2 p0 = cl[(16 + n0) * 8 + gg];
        int2 p1 = a1 ? cl[(17 + n0) * 8 + gg] : make_int2(0, 0);
        u16x8 va = *(const u16x8*)(vb + (size_t)p0.x * NQKV + e8);
        u16x8 vc = *(const u16x8*)(vb + (size_t)p1.x * NQKV + e8);
        float w0 = __int_as_float(p0.y);
        float w1 = a1 ? __int_as_float(p1.y) : 0.f;
        #pragma unroll
        for (int e = 0; e < 8; ++e) {
            acc[e] = fmaf(w0, bf2f(va[e]), acc[e]);
            acc[e] = fmaf(w1, bf2f(vc[e]), acc[e]);
        }
    }
    // reduce across the 8 row-groups
    #pragma unroll
    for (int m = 8; m <= 32; m <<= 1)
        #pragma unroll
        for (int e = 0; e < 8; ++e)
            acc[e] += __shfl_xor(acc[e], m);

    if (ln < 8) {
        float inv = 1.f / sum;
        float* op = &out[(size_t)bi * H_DIM + e8];
        *(float4*)op       = make_float4(acc[0]*inv, acc[1]*inv, acc[2]*inv, acc[3]*inv);
        *(float4*)(op + 4) = make_float4(acc[4]*inv, acc[5]*inv, acc[6]*inv, acc[7]*inv);
    }
}

// ---------------------------------------------------------------------------
extern "C" void kernel_launch(void* const* d_in, const int* in_sizes, int n_in,
                              void* d_out, int out_size, void* d_ws, size_t ws_size,
                              hipStream_t stream) {
    const float* x   = (const float*)d_in[0];
    const int*   rnd = (const int*)  d_in[1];
    const float* Wk  = (const float*)d_in[2];
    const float* Wq  = (const float*)d_in[3];
    const float* Wv  = (const float*)d_in[4];
    float* out = (float*)d_out;
    unsigned short* qkv = (unsigned short*)d_ws;   // 16384*192*2 = 6.3 MB

    proj_kernel<<<M_TOTAL / 64, 512, 0, stream>>>(x, Wk, Wq, Wv, qkv);
    attn_kernel<<<M_TOTAL / 4, 256, 0, stream>>>(qkv, rnd, out);
}

// Round 9
// 151.564 us; speedup vs baseline: 1.1852x; 1.0244x over previous
//
#include <hip/hip_runtime.h>
#include <math.h>

#define T_DIM 2048
#define C_DIM 1024
#define H_DIM 64
#define M_TOTAL 16384            // B*T
#define NQKV 192                 // k(0..63) | q(64..127) | v(128..191)

typedef __bf16 bf16x8 __attribute__((ext_vector_type(8)));
typedef float f32x4 __attribute__((ext_vector_type(4)));
typedef float f32x2 __attribute__((ext_vector_type(2)));
typedef unsigned short u16x8 __attribute__((ext_vector_type(8)));

#if __has_builtin(__builtin_amdgcn_fdot2_f32_bf16)
#define HAVE_DOT2 1
typedef __bf16 bf16x2 __attribute__((ext_vector_type(2)));
#else
#define HAVE_DOT2 0
#endif

__device__ __forceinline__ unsigned short f2bf(float f) {
    unsigned u = __float_as_uint(f);
    unsigned r = (u + 0x7FFFu + ((u >> 16) & 1u)) >> 16;   // RNE
    return (unsigned short)r;
}
__device__ __forceinline__ float bf2f(unsigned short u) {
    return __uint_as_float(((unsigned)u) << 16);
}
__device__ __forceinline__ float blo(unsigned u) { return __uint_as_float(u << 16); }
__device__ __forceinline__ float bhi(unsigned u) { return __uint_as_float(u & 0xFFFF0000u); }
// pack 2 floats -> 2 bf16 bits (round-half-up): 2x v_add + 1x v_perm
__device__ __forceinline__ unsigned pack_bf2(float f0, float f1) {
    unsigned u0 = __float_as_uint(f0) + 0x8000u;
    unsigned u1 = __float_as_uint(f1) + 0x8000u;
    return __builtin_amdgcn_perm(u1, u0, 0x07060302u);
}
__device__ __forceinline__ uint4 cvt8(float4 a, float4 b) {
    return make_uint4(pack_bf2(a.x, a.y), pack_bf2(a.z, a.w),
                      pack_bf2(b.x, b.y), pack_bf2(b.z, b.w));
}

// 8-elem bf16 dot: v_dot2_f32_bf16 when available, fma fallback.
__device__ __forceinline__ float dot8bf(u16x8 a, u16x8 b, float c) {
#if HAVE_DOT2
    bf16x8 av = __builtin_bit_cast(bf16x8, a);
    bf16x8 bv = __builtin_bit_cast(bf16x8, b);
    #pragma unroll
    for (int e = 0; e < 4; ++e) {
        bf16x2 ap = {av[2 * e], av[2 * e + 1]};
        bf16x2 bp = {bv[2 * e], bv[2 * e + 1]};
        c = __builtin_amdgcn_fdot2_f32_bf16(ap, bp, c, false);
    }
#else
    #pragma unroll
    for (int e = 0; e < 8; ++e) c = fmaf(bf2f(a[e]), bf2f(b[e]), c);
#endif
    return c;
}

// ---------------------------------------------------------------------------
// Kernel 1: fused convert + bf16 MFMA QKV projection (unchanged since R4).
// ---------------------------------------------------------------------------
__global__ __launch_bounds__(512) void proj_kernel(
    const float* __restrict__ x,
    const float* __restrict__ Wk,
    const float* __restrict__ Wq,
    const float* __restrict__ Wv,
    unsigned short* __restrict__ qkv)   // [16384][192] bf16 bits
{
    __shared__ unsigned short Ab[64 * 64];    // [row][k^swz]
    __shared__ unsigned short Bb[192 * 64];   // [col][k^swz]

    const int m0 = blockIdx.x * 64;
    const int t  = threadIdx.x;
    const int wv = t >> 6, ln = t & 63;
    const int mfr = ln & 15, kq = ln >> 4;
    const int r0 = (wv & 1) * 32;
    const int c0 = (wv >> 1) * 48;

    const int srow  = t >> 3;                // 0..63
    const int sk8   = (t & 7) * 8;
    const int skoff = sk8 ^ ((srow & 7) * 8);

    const float* gp[4] = {
        x  + (size_t)(m0 + srow) * C_DIM + sk8,
        Wk + (size_t)srow * C_DIM + sk8,
        Wq + (size_t)srow * C_DIM + sk8,
        Wv + (size_t)srow * C_DIM + sk8 };
    unsigned short* lp[4] = {
        &Ab[srow * 64 + skoff],
        &Bb[srow * 64 + skoff],
        &Bb[(srow + 64) * 64 + skoff],
        &Bb[(srow + 128) * 64 + skoff] };

    f32x4 acc[2][3] = {};

    float4 ra[4], rb[4];
    #pragma unroll
    for (int s = 0; s < 4; ++s) {
        ra[s] = *(const float4*)(gp[s]);
        rb[s] = *(const float4*)(gp[s] + 4);
    }

    for (int kc = 0; kc < C_DIM; kc += 64) {
        __syncthreads();
        #pragma unroll
        for (int s = 0; s < 4; ++s)
            *(uint4*)lp[s] = cvt8(ra[s], rb[s]);
        if (kc + 64 < C_DIM) {
            #pragma unroll
            for (int s = 0; s < 4; ++s) {
                ra[s] = *(const float4*)(gp[s] + kc + 64);
                rb[s] = *(const float4*)(gp[s] + kc + 68);
            }
        }
        __syncthreads();
        #pragma unroll
        for (int ks = 0; ks < 64; ks += 32) {
            bf16x8 af[2], bf[3];
            #pragma unroll
            for (int a = 0; a < 2; ++a) {
                int row = r0 + a * 16 + mfr;
                af[a] = *(const bf16x8*)&Ab[row * 64 + ((ks + kq * 8) ^ ((row & 7) * 8))];
            }
            #pragma unroll
            for (int b2 = 0; b2 < 3; ++b2) {
                int row = c0 + b2 * 16 + mfr;
                bf[b2] = *(const bf16x8*)&Bb[row * 64 + ((ks + kq * 8) ^ ((row & 7) * 8))];
            }
            #pragma unroll
            for (int a = 0; a < 2; ++a)
                #pragma unroll
                for (int b2 = 0; b2 < 3; ++b2)
                    acc[a][b2] = __builtin_amdgcn_mfma_f32_16x16x32_bf16(
                        af[a], bf[b2], acc[a][b2], 0, 0, 0);
        }
    }

    #pragma unroll
    for (int a = 0; a < 2; ++a)
        #pragma unroll
        for (int b2 = 0; b2 < 3; ++b2)
            #pragma unroll
            for (int r = 0; r < 4; ++r) {
                int row = m0 + r0 + a * 16 + kq * 4 + r;
                int col = c0 + b2 * 16 + mfr;
                qkv[(size_t)row * NQKV + col] = f2bf(acc[a][b2][r]);
            }
}

// ---------------------------------------------------------------------------
// Kernel 2: sparse BigBird attention — R5 structure (one wave per query,
// barrier-free, XCD swizzle, 8-lanes-per-row gathers, fixed 24 batches)
// + dot2 QK, computed local/global columns, f32-weight LDS table.
// Slot map: s in [0,64): local col = max(i-s,0); [64,128): global col s-64;
// [128,192): random col rj[s-128].
// ---------------------------------------------------------------------------
__global__ __launch_bounds__(256) void attn_kernel(
    const unsigned short* __restrict__ qkv,   // bf16 bits [16384][192]
    const int*  __restrict__ rnd,             // [2048][64]
    float* __restrict__ out)                  // [16384][64]
{
    const int wv = threadIdx.x >> 6;
    const int ln = threadIdx.x & 63;
    const int b  = blockIdx.x & 7;                  // XCD-locality swizzle
    const int i  = ((blockIdx.x >> 3) << 2) + wv;   // 0..2047
    const int bi = b * T_DIM + i;

    __shared__ float    wt_all[4][192];
    __shared__ int      rj_all[4][64];
    __shared__ unsigned bm_all[4][64];
    float*    wt = wt_all[wv];
    int*      rj = rj_all[wv];
    unsigned* bm = bm_all[wv];

    bm[ln] = 0u;

    // ---- candidate validity (registers) ----
    bool v0 = (ln <= i);                              // local slot ln -> col i-ln
    bool v1 = (ln < i - 63);                          // global col ln
    int  j2 = rnd[i * 64 + ln];
    bool v2 = (j2 < i - 63) && (j2 >= 64);
    if (v2) {   // dedup among randoms: winner of atomicOr keeps the column
        unsigned old = atomicOr(&bm[j2 >> 5], 1u << (j2 & 31));
        v2 = ((old >> (j2 & 31)) & 1u) == 0u;
    }
    rj[ln] = j2;                                      // raw (in [0,T)), safe loads

    // ---- q h-slice ----
    const int e8 = (ln & 7) * 8;     // h-slice base for this lane
    const int gg = ln >> 3;          // row-group within instruction 0..7
    u16x8 qraw = *(const u16x8*)(qkv + (size_t)bi * NQKV + 64 + e8);
#if !HAVE_DOT2
    float qr[8];
    #pragma unroll
    for (int e = 0; e < 8; ++e) qr[e] = bf2f(qraw[e]);
#endif

    const unsigned short* kb = qkv + (size_t)b * T_DIM * NQKV;

    // ---- QK: 24 batches (4-way MLP); columns computed, randoms from rj ----
    #pragma unroll
    for (int n = 0; n < 24; n += 4) {
        int jj[4];
        #pragma unroll
        for (int u = 0; u < 4; ++u) {
            int s = (n + u) * 8 + gg;
            int j;
            if (s < 64)       { j = i - s; j = (j < 0) ? 0 : j; }
            else if (s < 128) { j = s - 64; }
            else              { j = rj[s - 128]; }
            jj[u] = j;
        }
        u16x8 kv[4];
        #pragma unroll
        for (int u = 0; u < 4; ++u)
            kv[u] = *(const u16x8*)(kb + (size_t)jj[u] * NQKV + e8);
        #pragma unroll
        for (int u = 0; u < 4; ++u) {
            float p = dot8bf(kv[u], qraw, 0.f);
            p += __shfl_xor(p, 1);
            p += __shfl_xor(p, 2);
            p += __shfl_xor(p, 4);
            if ((ln & 7) == 0) wt[(n + u) * 8 + gg] = p;
        }
    }

    // ---- softmax: lane handles slots {ln, 64+ln, 128+ln} ----
    float s0 = wt[ln];
    float s1 = wt[64 + ln];
    float s2 = wt[128 + ln];
    s0 = v0 ? s0 * 0.125f : -1e30f;
    s1 = v1 ? s1 * 0.125f : -1e30f;
    s2 = v2 ? s2 * 0.125f : -1e30f;

    float mx = fmaxf(s0, fmaxf(s1, s2));
    #pragma unroll
    for (int m = 32; m; m >>= 1) mx = fmaxf(mx, __shfl_xor(mx, m));
    float e0 = v0 ? __expf(s0 - mx) : 0.f;
    float e1 = v1 ? __expf(s1 - mx) : 0.f;
    float e2 = v2 ? __expf(s2 - mx) : 0.f;
    float sum = e0 + e1 + e2;
    #pragma unroll
    for (int m = 32; m; m >>= 1) sum += __shfl_xor(sum, m);

    wt[ln]       = e0;
    wt[64 + ln]  = e1;
    wt[128 + ln] = e2;

    // ---- PV: 3 batches of 8 (8-way MLP), f32x2 pairs for pk_fma ----
    const unsigned short* vb = kb + 128;
    f32x2 acc2[4] = {};
    #pragma unroll
    for (int bt = 0; bt < 3; ++bt) {
        float w[8]; int jc[8];
        #pragma unroll
        for (int c = 0; c < 8; ++c) {
            int s = (bt * 8 + c) * 8 + gg;
            w[c] = wt[s];
            int j;
            if (s < 64)       { j = i - s; j = (j < 0) ? 0 : j; }
            else if (s < 128) { j = s - 64; }
            else              { j = rj[s - 128]; }
            jc[c] = j;
        }
        uint4 vv[8];
        #pragma unroll
        for (int c = 0; c < 8; ++c)
            vv[c] = *(const uint4*)(vb + (size_t)jc[c] * NQKV + e8);
        #pragma unroll
        for (int c = 0; c < 8; ++c) {
            f32x2 w2 = {w[c], w[c]};
            f32x2 p0 = {blo(vv[c].x), bhi(vv[c].x)};
            f32x2 p1 = {blo(vv[c].y), bhi(vv[c].y)};
            f32x2 p2 = {blo(vv[c].z), bhi(vv[c].z)};
            f32x2 p3 = {blo(vv[c].w), bhi(vv[c].w)};
            acc2[0] += w2 * p0;
            acc2[1] += w2 * p1;
            acc2[2] += w2 * p2;
            acc2[3] += w2 * p3;
        }
    }
    float acc[8] = { acc2[0][0], acc2[0][1], acc2[1][0], acc2[1][1],
                     acc2[2][0], acc2[2][1], acc2[3][0], acc2[3][1] };
    // reduce across the 8 row-groups
    #pragma unroll
    for (int m = 8; m <= 32; m <<= 1)
        #pragma unroll
        for (int e = 0; e < 8; ++e)
            acc[e] += __shfl_xor(acc[e], m);

    if (ln < 8) {
        float inv = 1.f / sum;
        float* op = &out[(size_t)bi * H_DIM + e8];
        *(float4*)op       = make_float4(acc[0]*inv, acc[1]*inv, acc[2]*inv, acc[3]*inv);
        *(float4*)(op + 4) = make_float4(acc[4]*inv, acc[5]*inv, acc[6]*inv, acc[7]*inv);
    }
}

// ---------------------------------------------------------------------------
extern "C" void kernel_launch(void* const* d_in, const int* in_sizes, int n_in,
                              void* d_out, int out_size, void* d_ws, size_t ws_size,
                              hipStream_t stream) {
    const float* x   = (const float*)d_in[0];
    const int*   rnd = (const int*)  d_in[1];
    const float* Wk  = (const float*)d_in[2];
    const float* Wq  = (const float*)d_in[3];
    const float* Wv  = (const float*)d_in[4];
    float* out = (float*)d_out;
    unsigned short* qkv = (unsigned short*)d_ws;   // 16384*192*2 = 6.3 MB

    proj_kernel<<<M_TOTAL / 64, 512, 0, stream>>>(x, Wk, Wq, Wv, qkv);
    attn_kernel<<<M_TOTAL / 4, 256, 0, stream>>>(qkv, rnd, out);
}

// Round 10
// 148.516 us; speedup vs baseline: 1.2096x; 1.0205x over previous
//
#include <hip/hip_runtime.h>
#include <math.h>

#define T_DIM 2048
#define C_DIM 1024
#define H_DIM 64
#define M_TOTAL 16384            // B*T
#define NQKV 192                 // k(0..63) | q(64..127) | v(128..191)

typedef __bf16 bf16x8 __attribute__((ext_vector_type(8)));
typedef float f32x4 __attribute__((ext_vector_type(4)));
typedef float f32x2 __attribute__((ext_vector_type(2)));
typedef unsigned short u16x8 __attribute__((ext_vector_type(8)));

#if __has_builtin(__builtin_amdgcn_fdot2_f32_bf16)
#define HAVE_DOT2 1
typedef __bf16 bf16x2 __attribute__((ext_vector_type(2)));
#else
#define HAVE_DOT2 0
#endif

__device__ __forceinline__ unsigned short f2bf(float f) {
    unsigned u = __float_as_uint(f);
    unsigned r = (u + 0x7FFFu + ((u >> 16) & 1u)) >> 16;   // RNE
    return (unsigned short)r;
}
__device__ __forceinline__ float bf2f(unsigned short u) {
    return __uint_as_float(((unsigned)u) << 16);
}
__device__ __forceinline__ float blo(unsigned u) { return __uint_as_float(u << 16); }
__device__ __forceinline__ float bhi(unsigned u) { return __uint_as_float(u & 0xFFFF0000u); }
// pack 2 floats -> 2 bf16 bits (round-half-up): 2x v_add + 1x v_perm
__device__ __forceinline__ unsigned pack_bf2(float f0, float f1) {
    unsigned u0 = __float_as_uint(f0) + 0x8000u;
    unsigned u1 = __float_as_uint(f1) + 0x8000u;
    return __builtin_amdgcn_perm(u1, u0, 0x07060302u);
}
__device__ __forceinline__ uint4 cvt8(float4 a, float4 b) {
    return make_uint4(pack_bf2(a.x, a.y), pack_bf2(a.z, a.w),
                      pack_bf2(b.x, b.y), pack_bf2(b.z, b.w));
}

// 8-elem bf16 dot: v_dot2_f32_bf16 when available, fma fallback.
__device__ __forceinline__ float dot8bf(u16x8 a, u16x8 b, float c) {
#if HAVE_DOT2
    bf16x8 av = __builtin_bit_cast(bf16x8, a);
    bf16x8 bv = __builtin_bit_cast(bf16x8, b);
    #pragma unroll
    for (int e = 0; e < 4; ++e) {
        bf16x2 ap = {av[2 * e], av[2 * e + 1]};
        bf16x2 bp = {bv[2 * e], bv[2 * e + 1]};
        c = __builtin_amdgcn_fdot2_f32_bf16(ap, bp, c, false);
    }
#else
    #pragma unroll
    for (int e = 0; e < 8; ++e) c = fmaf(bf2f(a[e]), bf2f(b[e]), c);
#endif
    return c;
}

// ---------------------------------------------------------------------------
// Kernel 1: fused convert + bf16 MFMA QKV projection (unchanged since R4).
// ---------------------------------------------------------------------------
__global__ __launch_bounds__(512) void proj_kernel(
    const float* __restrict__ x,
    const float* __restrict__ Wk,
    const float* __restrict__ Wq,
    const float* __restrict__ Wv,
    unsigned short* __restrict__ qkv)   // [16384][192] bf16 bits
{
    __shared__ unsigned short Ab[64 * 64];    // [row][k^swz]
    __shared__ unsigned short Bb[192 * 64];   // [col][k^swz]

    const int m0 = blockIdx.x * 64;
    const int t  = threadIdx.x;
    const int wv = t >> 6, ln = t & 63;
    const int mfr = ln & 15, kq = ln >> 4;
    const int r0 = (wv & 1) * 32;
    const int c0 = (wv >> 1) * 48;

    const int srow  = t >> 3;                // 0..63
    const int sk8   = (t & 7) * 8;
    const int skoff = sk8 ^ ((srow & 7) * 8);

    const float* gp[4] = {
        x  + (size_t)(m0 + srow) * C_DIM + sk8,
        Wk + (size_t)srow * C_DIM + sk8,
        Wq + (size_t)srow * C_DIM + sk8,
        Wv + (size_t)srow * C_DIM + sk8 };
    unsigned short* lp[4] = {
        &Ab[srow * 64 + skoff],
        &Bb[srow * 64 + skoff],
        &Bb[(srow + 64) * 64 + skoff],
        &Bb[(srow + 128) * 64 + skoff] };

    f32x4 acc[2][3] = {};

    float4 ra[4], rb[4];
    #pragma unroll
    for (int s = 0; s < 4; ++s) {
        ra[s] = *(const float4*)(gp[s]);
        rb[s] = *(const float4*)(gp[s] + 4);
    }

    for (int kc = 0; kc < C_DIM; kc += 64) {
        __syncthreads();
        #pragma unroll
        for (int s = 0; s < 4; ++s)
            *(uint4*)lp[s] = cvt8(ra[s], rb[s]);
        if (kc + 64 < C_DIM) {
            #pragma unroll
            for (int s = 0; s < 4; ++s) {
                ra[s] = *(const float4*)(gp[s] + kc + 64);
                rb[s] = *(const float4*)(gp[s] + kc + 68);
            }
        }
        __syncthreads();
        #pragma unroll
        for (int ks = 0; ks < 64; ks += 32) {
            bf16x8 af[2], bf[3];
            #pragma unroll
            for (int a = 0; a < 2; ++a) {
                int row = r0 + a * 16 + mfr;
                af[a] = *(const bf16x8*)&Ab[row * 64 + ((ks + kq * 8) ^ ((row & 7) * 8))];
            }
            #pragma unroll
            for (int b2 = 0; b2 < 3; ++b2) {
                int row = c0 + b2 * 16 + mfr;
                bf[b2] = *(const bf16x8*)&Bb[row * 64 + ((ks + kq * 8) ^ ((row & 7) * 8))];
            }
            #pragma unroll
            for (int a = 0; a < 2; ++a)
                #pragma unroll
                for (int b2 = 0; b2 < 3; ++b2)
                    acc[a][b2] = __builtin_amdgcn_mfma_f32_16x16x32_bf16(
                        af[a], bf[b2], acc[a][b2], 0, 0, 0);
        }
    }

    #pragma unroll
    for (int a = 0; a < 2; ++a)
        #pragma unroll
        for (int b2 = 0; b2 < 3; ++b2)
            #pragma unroll
            for (int r = 0; r < 4; ++r) {
                int row = m0 + r0 + a * 16 + kq * 4 + r;
                int col = c0 + b2 * 16 + mfr;
                qkv[(size_t)row * NQKV + col] = f2bf(acc[a][b2][r]);
            }
}

// ---------------------------------------------------------------------------
// Kernel 2: sparse BigBird attention — R9 structure (one wave per query,
// barrier-free, XCD swizzle, 8-lanes-per-row gathers, fully-unrolled 4-wide
// batches) + compacted randoms with WAVE-UNIFORM batch guards:
// valid randoms packed into rj[0..nval); random batches executed only when
// needed (nval>0 / nval>32). Pad slots: rj=0 (safe loads), weight 0.
// Slot map: s in [0,64): local col = max(i-s,0); [64,128): global col s-64;
// [128,192): compacted random rj[s-128], valid iff s-128 < nval.
// ---------------------------------------------------------------------------
__global__ __launch_bounds__(256) void attn_kernel(
    const unsigned short* __restrict__ qkv,   // bf16 bits [16384][192]
    const int*  __restrict__ rnd,             // [2048][64]
    float* __restrict__ out)                  // [16384][64]
{
    const int wv = threadIdx.x >> 6;
    const int ln = threadIdx.x & 63;
    const int b  = blockIdx.x & 7;                  // XCD-locality swizzle
    const int i  = ((blockIdx.x >> 3) << 2) + wv;   // 0..2047
    const int bi = b * T_DIM + i;

    __shared__ float    wt_all[4][192];
    __shared__ int      rj_all[4][64];
    __shared__ unsigned bm_all[4][64];
    float*    wt = wt_all[wv];
    int*      rj = rj_all[wv];
    unsigned* bm = bm_all[wv];

    bm[ln] = 0u;
    rj[ln] = 0;      // pad default (safe col 0); overwritten by compaction

    // ---- candidate validity + random dedup/compaction ----
    bool v0 = (ln <= i);                              // local slot ln -> col i-ln
    bool v1 = (ln < i - 63);                          // global col ln
    int  j2 = rnd[i * 64 + ln];
    bool v2 = (j2 < i - 63) && (j2 >= 64);
    if (v2) {   // dedup among randoms: winner of atomicOr keeps the column
        unsigned old = atomicOr(&bm[j2 >> 5], 1u << (j2 & 31));
        v2 = ((old >> (j2 & 31)) & 1u) == 0u;
    }
    unsigned long long mbal = __ballot(v2);
    const int nval = __popcll(mbal);                  // wave-uniform
    if (v2) {
        int pos = __popcll(mbal & ((1ull << ln) - 1ull));
        rj[pos] = j2;                                 // same-wave DS order: after rj[ln]=0
    }

    // ---- q h-slice ----
    const int e8 = (ln & 7) * 8;     // h-slice base for this lane
    const int gg = ln >> 3;          // row-group within instruction 0..7
    u16x8 qraw = *(const u16x8*)(qkv + (size_t)bi * NQKV + 64 + e8);

    const unsigned short* kb = qkv + (size_t)b * T_DIM * NQKV;

    // ---- QK locals+globals: 16 fixed batches (4-way MLP) ----
    #pragma unroll
    for (int n = 0; n < 16; n += 4) {
        int jj[4];
        #pragma unroll
        for (int u = 0; u < 4; ++u) {
            int s = (n + u) * 8 + gg;
            int j;
            if (s < 64) { j = i - s; j = (j < 0) ? 0 : j; }
            else        { j = s - 64; }
            jj[u] = j;
        }
        u16x8 kv[4];
        #pragma unroll
        for (int u = 0; u < 4; ++u)
            kv[u] = *(const u16x8*)(kb + (size_t)jj[u] * NQKV + e8);
        #pragma unroll
        for (int u = 0; u < 4; ++u) {
            float p = dot8bf(kv[u], qraw, 0.f);
            p += __shfl_xor(p, 1);
            p += __shfl_xor(p, 2);
            p += __shfl_xor(p, 4);
            if ((ln & 7) == 0) wt[(n + u) * 8 + gg] = p;
        }
    }

    // ---- QK randoms: compacted, wave-uniform guarded 4-wide batches ----
    auto qk_rand = [&](int n0) {   // n0 in {16, 20}; covers random idx (n0-16)*8 .. +31
        int jj[4];
        #pragma unroll
        for (int u = 0; u < 4; ++u) jj[u] = rj[(n0 - 16 + u) * 8 + gg];
        u16x8 kv[4];
        #pragma unroll
        for (int u = 0; u < 4; ++u)
            kv[u] = *(const u16x8*)(kb + (size_t)jj[u] * NQKV + e8);
        #pragma unroll
        for (int u = 0; u < 4; ++u) {
            float p = dot8bf(kv[u], qraw, 0.f);
            p += __shfl_xor(p, 1);
            p += __shfl_xor(p, 2);
            p += __shfl_xor(p, 4);
            if ((ln & 7) == 0) wt[(n0 + u) * 8 + gg] = p;
        }
    };
    if (nval > 0)  qk_rand(16);
    if (nval > 32) qk_rand(20);
    // (unwritten wt slots >= nval are masked by vs2 below before any use)

    // ---- softmax: lane handles slots {ln, 64+ln, 128+ln} ----
    const bool vs2 = (ln < nval);
    float s0 = wt[ln];
    float s1 = wt[64 + ln];
    float s2 = vs2 ? wt[128 + ln] : 0.f;
    s0 = v0  ? s0 * 0.125f : -1e30f;
    s1 = v1  ? s1 * 0.125f : -1e30f;
    s2 = vs2 ? s2 * 0.125f : -1e30f;

    float mx = fmaxf(s0, fmaxf(s1, s2));
    #pragma unroll
    for (int m = 32; m; m >>= 1) mx = fmaxf(mx, __shfl_xor(mx, m));
    float e0 = v0  ? __expf(s0 - mx) : 0.f;
    float e1 = v1  ? __expf(s1 - mx) : 0.f;
    float e2 = vs2 ? __expf(s2 - mx) : 0.f;
    float sum = e0 + e1 + e2;
    #pragma unroll
    for (int m = 32; m; m >>= 1) sum += __shfl_xor(sum, m);

    wt[ln]       = e0;
    wt[64 + ln]  = e1;
    wt[128 + ln] = e2;     // pads get 0 -> safe to multiply in executed batches

    // ---- PV locals+globals: 2 fixed batches of 8 (8-way MLP) ----
    const unsigned short* vb = kb + 128;
    f32x2 acc2[4] = {};
    #pragma unroll
    for (int bt = 0; bt < 2; ++bt) {
        float w[8]; int jc[8];
        #pragma unroll
        for (int c = 0; c < 8; ++c) {
            int s = (bt * 8 + c) * 8 + gg;
            w[c] = wt[s];
            int j;
            if (s < 64) { j = i - s; j = (j < 0) ? 0 : j; }
            else        { j = s - 64; }
            jc[c] = j;
        }
        uint4 vv[8];
        #pragma unroll
        for (int c = 0; c < 8; ++c)
            vv[c] = *(const uint4*)(vb + (size_t)jc[c] * NQKV + e8);
        #pragma unroll
        for (int c = 0; c < 8; ++c) {
            f32x2 w2 = {w[c], w[c]};
            f32x2 p0 = {blo(vv[c].x), bhi(vv[c].x)};
            f32x2 p1 = {blo(vv[c].y), bhi(vv[c].y)};
            f32x2 p2 = {blo(vv[c].z), bhi(vv[c].z)};
            f32x2 p3 = {blo(vv[c].w), bhi(vv[c].w)};
            acc2[0] += w2 * p0;
            acc2[1] += w2 * p1;
            acc2[2] += w2 * p2;
            acc2[3] += w2 * p3;
        }
    }
    // ---- PV randoms: compacted, wave-uniform guarded 4-wide batches ----
    auto pv_rand = [&](int c0) {   // c0 in {0, 4}; covers random idx c0*8 .. +31
        float w[4]; int jc[4];
        #pragma unroll
        for (int c = 0; c < 4; ++c) {
            int ridx = (c0 + c) * 8 + gg;
            w[c]  = wt[128 + ridx];
            jc[c] = rj[ridx];
        }
        uint4 vv[4];
        #pragma unroll
        for (int c = 0; c < 4; ++c)
            vv[c] = *(const uint4*)(vb + (size_t)jc[c] * NQKV + e8);
        #pragma unroll
        for (int c = 0; c < 4; ++c) {
            f32x2 w2 = {w[c], w[c]};
            f32x2 p0 = {blo(vv[c].x), bhi(vv[c].x)};
            f32x2 p1 = {blo(vv[c].y), bhi(vv[c].y)};
            f32x2 p2 = {blo(vv[c].z), bhi(vv[c].z)};
            f32x2 p3 = {blo(vv[c].w), bhi(vv[c].w)};
            acc2[0] += w2 * p0;
            acc2[1] += w2 * p1;
            acc2[2] += w2 * p2;
            acc2[3] += w2 * p3;
        }
    };
    if (nval > 0)  pv_rand(0);
    if (nval > 32) pv_rand(4);

    float acc[8] = { acc2[0][0], acc2[0][1], acc2[1][0], acc2[1][1],
                     acc2[2][0], acc2[2][1], acc2[3][0], acc2[3][1] };
    // reduce across the 8 row-groups
    #pragma unroll
    for (int m = 8; m <= 32; m <<= 1)
        #pragma unroll
        for (int e = 0; e < 8; ++e)
            acc[e] += __shfl_xor(acc[e], m);

    if (ln < 8) {
        float inv = 1.f / sum;
        float* op = &out[(size_t)bi * H_DIM + e8];
        *(float4*)op       = make_float4(acc[0]*inv, acc[1]*inv, acc[2]*inv, acc[3]*inv);
        *(float4*)(op + 4) = make_float4(acc[4]*inv, acc[5]*inv, acc[6]*inv, acc[7]*inv);
    }
}

// ---------------------------------------------------------------------------
extern "C" void kernel_launch(void* const* d_in, const int* in_sizes, int n_in,
                              void* d_out, int out_size, void* d_ws, size_t ws_size,
                              hipStream_t stream) {
    const float* x   = (const float*)d_in[0];
    const int*   rnd = (const int*)  d_in[1];
    const float* Wk  = (const float*)d_in[2];
    const float* Wq  = (const float*)d_in[3];
    const float* Wv  = (const float*)d_in[4];
    float* out = (float*)d_out;
    unsigned short* qkv = (unsigned short*)d_ws;   // 16384*192*2 = 6.3 MB

    proj_kernel<<<M_TOTAL / 64, 512, 0, stream>>>(x, Wk, Wq, Wv, qkv);
    attn_kernel<<<M_TOTAL / 4, 256, 0, stream>>>(qkv, rnd, out);
}